// Round 1
// baseline (2289.470 us; speedup 1.0000x reference)
//
#include <hip/hip_runtime.h>
#include <math.h>

#define TPB 256

// ---------------------------------------------------------------------------
// Edge dtype probe: if edge_index is int64 (little-endian, values < 2^31),
// every odd 32-bit word is zero. For genuine int32 random node ids the odds
// of 2048 consecutive odd words all being zero are ~0. flag=1 -> int32.
// ---------------------------------------------------------------------------
__global__ __launch_bounds__(TPB) void detect_dtype(const int* __restrict__ e,
                                                    int* __restrict__ flag) {
  __shared__ int found;
  if (threadIdx.x == 0) found = 0;
  __syncthreads();
  int nz = 0;
  for (int i = threadIdx.x; i < 2048; i += TPB)
    nz |= (e[2 * i + 1] != 0) ? 1 : 0;
  if (nz) atomicOr(&found, 1);
  __syncthreads();
  if (threadIdx.x == 0) *flag = found;
}

__global__ __launch_bounds__(TPB) void init_deg(float* __restrict__ deg, int n) {
  int i = blockIdx.x * TPB + threadIdx.x;
  if (i < n) deg[i] = 1.0f;  // self-loop
}

// Convert edges to int32 (handles int32 or int64 input) and count in-degrees
// of dst (second half of the buffer) in the same pass.
__global__ __launch_bounds__(TPB) void convert_count(const void* __restrict__ eptr,
                                                     int* __restrict__ e32,
                                                     float* __restrict__ deg,
                                                     const int* __restrict__ flag,
                                                     int total, int E) {
  int i = blockIdx.x * TPB + threadIdx.x;
  if (i >= total) return;
  int v;
  if (*flag)
    v = ((const int*)eptr)[i];
  else
    v = (int)(((const long long*)eptr)[i]);
  e32[i] = v;
  if (i >= E) unsafeAtomicAdd(&deg[v], 1.0f);
}

__global__ __launch_bounds__(TPB) void compute_dinv(float* __restrict__ deg, int n) {
  int i = blockIdx.x * TPB + threadIdx.x;
  if (i < n) deg[i] = rsqrtf(deg[i]);
}

// ---------------------------------------------------------------------------
// out[r, c] = (A[r,:] @ W[:,c]) * dinv[r]      (t = h*W scaled by dinv[row])
// Block: 256 threads, 8 rows x NC cols. A rows staged in LDS.
// ---------------------------------------------------------------------------
template <int K, int NC>
__global__ __launch_bounds__(TPB) void gemm_scale(const float* __restrict__ A,
                                                  const float* __restrict__ W,
                                                  const float* __restrict__ dinv,
                                                  float* __restrict__ out, int nrows) {
  constexpr int ROWS = 8;
  constexpr int GROUPS = TPB / NC;    // 2 (NC=128) or 4 (NC=64)
  constexpr int RPT = ROWS / GROUPS;  // 4 or 2
  __shared__ float As[ROWS * K];

  int block_row = blockIdx.x * ROWS;
  int tid = threadIdx.x;

  // cooperative stage of 8 A rows (ROWS*K floats, float4 per thread)
  {
    int idx = tid * 4;
    int r = idx / K, c = idx % K;
    int gr = block_row + r;
    float4 v = make_float4(0.f, 0.f, 0.f, 0.f);
    if (gr < nrows) v = *(const float4*)&A[(size_t)gr * K + c];
    *(float4*)&As[idx] = v;
  }
  __syncthreads();

  int c = tid % NC;
  int g = tid / NC;
  int r0 = g * RPT;

  float acc[RPT];
#pragma unroll
  for (int r = 0; r < RPT; r++) acc[r] = 0.f;

  for (int k = 0; k < K; k += 4) {
    float w0 = W[(k + 0) * NC + c];
    float w1 = W[(k + 1) * NC + c];
    float w2 = W[(k + 2) * NC + c];
    float w3 = W[(k + 3) * NC + c];
#pragma unroll
    for (int r = 0; r < RPT; r++) {
      float4 a = *(const float4*)&As[(r0 + r) * K + k];  // wave-uniform broadcast
      acc[r] += a.x * w0 + a.y * w1 + a.z * w2 + a.w * w3;
    }
  }

#pragma unroll
  for (int r = 0; r < RPT; r++) {
    int gr = block_row + r0 + r;
    if (gr < nrows) out[(size_t)gr * NC + c] = acc[r] * dinv[gr];
  }
}

// ---------------------------------------------------------------------------
// Edge scatter: agg[dst] += t[src] (t already scaled by dinv[src]).
// NC/4 lanes per edge, float4 gather + 4 HW fp32 atomics.
// ---------------------------------------------------------------------------
template <int NC>
__global__ __launch_bounds__(TPB) void scatter_add(const int* __restrict__ src,
                                                   const int* __restrict__ dst,
                                                   const float* __restrict__ t,
                                                   float* __restrict__ agg, int E) {
  constexpr int LANES = NC / 4;
  int gt = blockIdx.x * TPB + threadIdx.x;
  int edge = gt / LANES;
  int l = gt % LANES;
  if (edge >= E) return;
  int s = src[edge];
  int d = dst[edge];
  float4 v = *(const float4*)&t[(size_t)s * NC + l * 4];
  float* p = &agg[(size_t)d * NC + l * 4];
  unsafeAtomicAdd(p + 0, v.x);
  unsafeAtomicAdd(p + 1, v.y);
  unsafeAtomicAdd(p + 2, v.z);
  unsafeAtomicAdd(p + 3, v.w);
}

// ---------------------------------------------------------------------------
// h[i,c] = tanh((agg[i,c] + t[i,c]) * dinv[i] + b[c])   (t term = self-loop)
// In-place into agg. float4 per thread.
// ---------------------------------------------------------------------------
template <int NC>
__global__ __launch_bounds__(TPB) void finalize_tanh(float* __restrict__ agg,
                                                     const float* __restrict__ t,
                                                     const float* __restrict__ dinv,
                                                     const float* __restrict__ bias,
                                                     int n) {
  int i = blockIdx.x * TPB + threadIdx.x;
  int total = n * (NC / 4);
  if (i >= total) return;
  int row = i / (NC / 4);
  int c4 = i % (NC / 4);
  float di = dinv[row];
  float4 a = *(const float4*)&agg[(size_t)i * 4];
  float4 h = *(const float4*)&t[(size_t)i * 4];
  float4 b = *(const float4*)&bias[c4 * 4];
  float4 r;
  r.x = tanhf((a.x + h.x) * di + b.x);
  r.y = tanhf((a.y + h.y) * di + b.y);
  r.z = tanhf((a.z + h.z) * di + b.z);
  r.w = tanhf((a.w + h.w) * di + b.w);
  *(float4*)&agg[(size_t)i * 4] = r;
}

// ---------------------------------------------------------------------------
// out[r] = tanh(h2[r,:] @ Wf1 + bf1) @ Wf2 + bf2 ; one thread per row.
// Weights read via uniform (scalar) loads.
// ---------------------------------------------------------------------------
__global__ __launch_bounds__(TPB) void mlp_head(const float* __restrict__ h2,
                                                const float* __restrict__ Wf1,
                                                const float* __restrict__ bf1,
                                                const float* __restrict__ Wf2,
                                                const float* __restrict__ bf2,
                                                float* __restrict__ out, int n) {
  int row = blockIdx.x * TPB + threadIdx.x;
  if (row >= n) return;
  float acc[32];
#pragma unroll
  for (int j = 0; j < 32; j++) acc[j] = bf1[j];
#pragma unroll 4
  for (int k = 0; k < 64; k += 4) {
    float4 h4 = *(const float4*)&h2[(size_t)row * 64 + k];
    float hv[4] = {h4.x, h4.y, h4.z, h4.w};
#pragma unroll
    for (int kk = 0; kk < 4; kk++)
#pragma unroll
      for (int j = 0; j < 32; j++) acc[j] += hv[kk] * Wf1[(k + kk) * 32 + j];
  }
  float o = bf2[0];
#pragma unroll
  for (int j = 0; j < 32; j++) o += tanhf(acc[j]) * Wf2[j];
  out[row] = o;
}

extern "C" void kernel_launch(void* const* d_in, const int* in_sizes, int n_in,
                              void* d_out, int out_size, void* d_ws, size_t ws_size,
                              hipStream_t stream) {
  const float* x   = (const float*)d_in[0];
  const void*  eix = d_in[1];
  const float* W1  = (const float*)d_in[2];
  const float* b1  = (const float*)d_in[3];
  const float* W2  = (const float*)d_in[4];
  const float* b2  = (const float*)d_in[5];
  const float* Wf1 = (const float*)d_in[6];
  const float* bf1 = (const float*)d_in[7];
  const float* Wf2 = (const float*)d_in[8];
  const float* bf2 = (const float*)d_in[9];
  float* out = (float*)d_out;

  const int N = in_sizes[0] / 128;
  const int E = in_sizes[1] / 2;

  // workspace layout (bytes, 16B aligned)
  char* ws = (char*)d_ws;
  size_t off = 0;
  float* deg = (float*)(ws + off); off += (size_t)N * 4;            // deg -> dinv in place
  off = (off + 15) & ~(size_t)15;
  int* e32 = (int*)(ws + off); off += (size_t)2 * E * 4;            // src | dst as int32
  int* flag = (int*)(ws + off); off += 64;                           // dtype flag
  float* h1s = (float*)(ws + off); off += (size_t)N * 128 * 4;       // t1; later t2|agg2
  float* agg1 = (float*)(ws + off); off += (size_t)N * 128 * 4;      // agg1 -> h1 in place
  int* src = e32;
  int* dst = e32 + E;
  float* h2s = h1s;                 // N*64, reuses t1 region
  float* agg2 = h1s + (size_t)N * 64;  // N*64, second half of t1 region
  (void)ws_size; (void)n_in; (void)out_size;

  const int nb = [](int a, int b) { return (a + b - 1) / b; }(N, TPB);

  // degree + edge conversion
  detect_dtype<<<1, TPB, 0, stream>>>((const int*)eix, flag);
  init_deg<<<nb, TPB, 0, stream>>>(deg, N);
  convert_count<<<(2 * E + TPB - 1) / TPB, TPB, 0, stream>>>(eix, e32, deg, flag, 2 * E, E);
  compute_dinv<<<nb, TPB, 0, stream>>>(deg, N);

  // layer 1: t1 = (x@W1)*dinv ; agg1 = scatter(t1) ; h1 = tanh((agg1+t1)*dinv+b1)
  gemm_scale<128, 128><<<nb * (TPB / 8) / (TPB / 8), TPB, 0, stream>>>(x, W1, deg, h1s, N);
  // (grid = ceil(N/8))
  gemm_scale<128, 128><<<(N + 7) / 8, TPB, 0, stream>>>(x, W1, deg, h1s, N);
  hipMemsetAsync(agg1, 0, (size_t)N * 128 * 4, stream);
  scatter_add<128><<<((size_t)E * 32 + TPB - 1) / TPB, TPB, 0, stream>>>(src, dst, h1s, agg1, E);
  finalize_tanh<128><<<(N * 32 + TPB - 1) / TPB, TPB, 0, stream>>>(agg1, h1s, deg, b1, N);

  // layer 2: t2 = (h1@W2)*dinv ; agg2 = scatter(t2) ; h2 = tanh((agg2+t2)*dinv+b2)
  gemm_scale<128, 64><<<(N + 7) / 8, TPB, 0, stream>>>(agg1, W2, deg, h2s, N);
  hipMemsetAsync(agg2, 0, (size_t)N * 64 * 4, stream);
  scatter_add<64><<<((size_t)E * 16 + TPB - 1) / TPB, TPB, 0, stream>>>(src, dst, h2s, agg2, E);
  finalize_tanh<64><<<(N * 16 + TPB - 1) / TPB, TPB, 0, stream>>>(agg2, h2s, deg, b2, N);

  // MLP head
  mlp_head<<<nb, TPB, 0, stream>>>(agg2, Wf1, bf1, Wf2, bf2, out, N);
}

// Round 2
// 670.901 us; speedup vs baseline: 3.4125x; 3.4125x over previous
//
#include <hip/hip_runtime.h>
#include <math.h>

#define TPB 256

// ---------------------------------------------------------------------------
// Edge dtype probe: if edge_index is int64 (LE, values < 2^31), every odd
// 32-bit word is zero. flag=1 -> int32 input.
// ---------------------------------------------------------------------------
__global__ __launch_bounds__(TPB) void detect_dtype(const int* __restrict__ e,
                                                    int* __restrict__ flag) {
  __shared__ int found;
  if (threadIdx.x == 0) found = 0;
  __syncthreads();
  int nz = 0;
  for (int i = threadIdx.x; i < 2048; i += TPB)
    nz |= (e[2 * i + 1] != 0) ? 1 : 0;
  if (nz) atomicOr(&found, 1);
  __syncthreads();
  if (threadIdx.x == 0) *flag = found;
}

__global__ __launch_bounds__(TPB) void init_deg(float* __restrict__ deg, int n) {
  int i = blockIdx.x * TPB + threadIdx.x;
  if (i < n) deg[i] = 1.0f;  // self-loop
}

// Convert edges to int32 (int32 or int64 input) and count in-degrees of dst
// (second half of buffer) in the same pass.
__global__ __launch_bounds__(TPB) void convert_count(const void* __restrict__ eptr,
                                                     int* __restrict__ e32,
                                                     float* __restrict__ deg,
                                                     const int* __restrict__ flag,
                                                     int total, int E) {
  int i = blockIdx.x * TPB + threadIdx.x;
  if (i >= total) return;
  int v;
  if (*flag)
    v = ((const int*)eptr)[i];
  else
    v = (int)(((const long long*)eptr)[i]);
  e32[i] = v;
  if (i >= E) unsafeAtomicAdd(&deg[v], 1.0f);
}

// Exclusive prefix-sum of integer in-degrees (deg[i]-1, deg still raw float
// counts) into rowptr. Single block, serial over chunks with carry.
__global__ __launch_bounds__(TPB) void scan_deg(const float* __restrict__ deg,
                                                int* __restrict__ rowptr, int n) {
  __shared__ int buf[TPB];
  __shared__ int carry;
  int tid = threadIdx.x;
  if (tid == 0) carry = 0;
  __syncthreads();
  for (int base = 0; base < n; base += TPB) {
    int i = base + tid;
    int v = (i < n) ? (int)(deg[i] + 0.5f) - 1 : 0;
    buf[tid] = v;
    __syncthreads();
    for (int off = 1; off < TPB; off <<= 1) {
      int t = (tid >= off) ? buf[tid - off] : 0;
      __syncthreads();
      buf[tid] += t;
      __syncthreads();
    }
    int incl = buf[tid];
    if (i < n) rowptr[i] = carry + incl - v;  // exclusive
    __syncthreads();
    if (tid == TPB - 1) carry += incl;
    __syncthreads();
  }
}

__global__ __launch_bounds__(TPB) void compute_dinv(float* __restrict__ deg, int n) {
  int i = blockIdx.x * TPB + threadIdx.x;
  if (i < n) deg[i] = rsqrtf(deg[i]);
}

// CSR fill, cursor trick: slot = rowptr[d]++ (atomic). After this kernel,
// rowptr[i] = end offset of node i; start = (i==0) ? 0 : rowptr[i-1].
__global__ __launch_bounds__(TPB) void csr_fill(const int* __restrict__ src,
                                                const int* __restrict__ dst,
                                                int* __restrict__ rowptr,
                                                int* __restrict__ csr_src, int E) {
  int e = blockIdx.x * TPB + threadIdx.x;
  if (e >= E) return;
  int slot = atomicAdd(&rowptr[dst[e]], 1);
  csr_src[slot] = src[e];
}

// ---------------------------------------------------------------------------
// out[r, c] = (A[r,:] @ W[:,c]) * dinv[r]
// ---------------------------------------------------------------------------
template <int K, int NC>
__global__ __launch_bounds__(TPB) void gemm_scale(const float* __restrict__ A,
                                                  const float* __restrict__ W,
                                                  const float* __restrict__ dinv,
                                                  float* __restrict__ out, int nrows) {
  constexpr int ROWS = 8;
  constexpr int GROUPS = TPB / NC;
  constexpr int RPT = ROWS / GROUPS;
  __shared__ float As[ROWS * K];

  int block_row = blockIdx.x * ROWS;
  int tid = threadIdx.x;

  {
    int idx = tid * 4;
    int r = idx / K, c = idx % K;
    int gr = block_row + r;
    float4 v = make_float4(0.f, 0.f, 0.f, 0.f);
    if (gr < nrows) v = *(const float4*)&A[(size_t)gr * K + c];
    *(float4*)&As[idx] = v;
  }
  __syncthreads();

  int c = tid % NC;
  int g = tid / NC;
  int r0 = g * RPT;

  float acc[RPT];
#pragma unroll
  for (int r = 0; r < RPT; r++) acc[r] = 0.f;

  for (int k = 0; k < K; k += 4) {
    float w0 = W[(k + 0) * NC + c];
    float w1 = W[(k + 1) * NC + c];
    float w2 = W[(k + 2) * NC + c];
    float w3 = W[(k + 3) * NC + c];
#pragma unroll
    for (int r = 0; r < RPT; r++) {
      float4 a = *(const float4*)&As[(r0 + r) * K + k];
      acc[r] += a.x * w0 + a.y * w1 + a.z * w2 + a.w * w3;
    }
  }

#pragma unroll
  for (int r = 0; r < RPT; r++) {
    int gr = block_row + r0 + r;
    if (gr < nrows) out[(size_t)gr * NC + c] = acc[r] * dinv[gr];
  }
}

// ---------------------------------------------------------------------------
// Fused CSR aggregation + self-loop + dinv scale + bias + tanh:
//   h[i,:] = tanh((sum_{s in in(i)} t[s,:] + t[i,:]) * dinv[i] + b)
// NC/4 lanes per node, float4 gathers, one coalesced write. No atomics.
// ---------------------------------------------------------------------------
template <int NC>
__global__ __launch_bounds__(TPB) void gcn_aggregate(const int* __restrict__ rowend,
                                                     const int* __restrict__ csr_src,
                                                     const float* __restrict__ t,
                                                     const float* __restrict__ dinv,
                                                     const float* __restrict__ bias,
                                                     float* __restrict__ h, int n) {
  constexpr int LPN = NC / 4;          // lanes per node
  constexpr int NPB = TPB / LPN;       // nodes per block
  int tid = threadIdx.x;
  int node = blockIdx.x * NPB + tid / LPN;
  int lane = tid % LPN;
  if (node >= n) return;

  int start = (node == 0) ? 0 : rowend[node - 1];
  int end = rowend[node];

  float4 acc = make_float4(0.f, 0.f, 0.f, 0.f);
  for (int e = start; e < end; e++) {
    int s = csr_src[e];
    float4 v = *(const float4*)&t[(size_t)s * NC + lane * 4];
    acc.x += v.x; acc.y += v.y; acc.z += v.z; acc.w += v.w;
  }
  float4 self = *(const float4*)&t[(size_t)node * NC + lane * 4];
  float di = dinv[node];
  float4 b = *(const float4*)&bias[lane * 4];
  float4 r;
  r.x = tanhf((acc.x + self.x) * di + b.x);
  r.y = tanhf((acc.y + self.y) * di + b.y);
  r.z = tanhf((acc.z + self.z) * di + b.z);
  r.w = tanhf((acc.w + self.w) * di + b.w);
  *(float4*)&h[(size_t)node * NC + lane * 4] = r;
}

// ---------------------------------------------------------------------------
// out[r] = tanh(h2[r,:] @ Wf1 + bf1) @ Wf2 + bf2 ; one thread per row.
// ---------------------------------------------------------------------------
__global__ __launch_bounds__(TPB) void mlp_head(const float* __restrict__ h2,
                                                const float* __restrict__ Wf1,
                                                const float* __restrict__ bf1,
                                                const float* __restrict__ Wf2,
                                                const float* __restrict__ bf2,
                                                float* __restrict__ out, int n) {
  int row = blockIdx.x * TPB + threadIdx.x;
  if (row >= n) return;
  float acc[32];
#pragma unroll
  for (int j = 0; j < 32; j++) acc[j] = bf1[j];
#pragma unroll 4
  for (int k = 0; k < 64; k += 4) {
    float4 h4 = *(const float4*)&h2[(size_t)row * 64 + k];
    float hv[4] = {h4.x, h4.y, h4.z, h4.w};
#pragma unroll
    for (int kk = 0; kk < 4; kk++)
#pragma unroll
      for (int j = 0; j < 32; j++) acc[j] += hv[kk] * Wf1[(k + kk) * 32 + j];
  }
  float o = bf2[0];
#pragma unroll
  for (int j = 0; j < 32; j++) o += tanhf(acc[j]) * Wf2[j];
  out[row] = o;
}

extern "C" void kernel_launch(void* const* d_in, const int* in_sizes, int n_in,
                              void* d_out, int out_size, void* d_ws, size_t ws_size,
                              hipStream_t stream) {
  const float* x   = (const float*)d_in[0];
  const void*  eix = d_in[1];
  const float* W1  = (const float*)d_in[2];
  const float* b1  = (const float*)d_in[3];
  const float* W2  = (const float*)d_in[4];
  const float* b2  = (const float*)d_in[5];
  const float* Wf1 = (const float*)d_in[6];
  const float* bf1 = (const float*)d_in[7];
  const float* Wf2 = (const float*)d_in[8];
  const float* bf2 = (const float*)d_in[9];
  float* out = (float*)d_out;

  const int N = in_sizes[0] / 128;
  const int E = in_sizes[1] / 2;

  // workspace layout (16B aligned)
  char* ws = (char*)d_ws;
  size_t off = 0;
  float* deg = (float*)(ws + off); off += (size_t)N * 4;        // counts -> dinv
  int* flag = (int*)(ws + off); off += 64;
  int* e32 = (int*)(ws + off); off += (size_t)2 * E * 4;        // src | dst int32
  int* rowptr = (int*)(ws + off); off += ((size_t)N + 4) * 4;   // excl psum -> rowend
  int* csr_src = (int*)(ws + off); off += (size_t)E * 4;
  off = (off + 15) & ~(size_t)15;
  float* t1 = (float*)(ws + off); off += (size_t)N * 128 * 4;   // t1; later t2|h2
  float* h1 = (float*)(ws + off); off += (size_t)N * 128 * 4;
  int* src = e32;
  int* dst = e32 + E;
  float* t2 = t1;                        // N*64, reuses t1 region
  float* h2 = t1 + (size_t)N * 64;       // N*64
  (void)ws_size; (void)n_in; (void)out_size;

  const int nb = (N + TPB - 1) / TPB;

  // graph preprocessing: dtype, degrees, dinv, CSR
  detect_dtype<<<1, TPB, 0, stream>>>((const int*)eix, flag);
  init_deg<<<nb, TPB, 0, stream>>>(deg, N);
  convert_count<<<(2 * E + TPB - 1) / TPB, TPB, 0, stream>>>(eix, e32, deg, flag, 2 * E, E);
  scan_deg<<<1, TPB, 0, stream>>>(deg, rowptr, N);
  compute_dinv<<<nb, TPB, 0, stream>>>(deg, N);
  csr_fill<<<(E + TPB - 1) / TPB, TPB, 0, stream>>>(src, dst, rowptr, csr_src, E);

  // layer 1: t1 = (x@W1)*dinv ; h1 = tanh((gather(t1)+t1)*dinv+b1)
  gemm_scale<128, 128><<<(N + 7) / 8, TPB, 0, stream>>>(x, W1, deg, t1, N);
  gcn_aggregate<128><<<(N + 7) / 8, TPB, 0, stream>>>(rowptr, csr_src, t1, deg, b1, h1, N);

  // layer 2: t2 = (h1@W2)*dinv ; h2 = tanh((gather(t2)+t2)*dinv+b2)
  gemm_scale<128, 64><<<(N + 7) / 8, TPB, 0, stream>>>(h1, W2, deg, t2, N);
  gcn_aggregate<64><<<(N + 15) / 16, TPB, 0, stream>>>(rowptr, csr_src, t2, deg, b2, h2, N);

  // MLP head
  mlp_head<<<nb, TPB, 0, stream>>>(h2, Wf1, bf1, Wf2, bf2, out, N);
}

// Round 3
// 452.553 us; speedup vs baseline: 5.0590x; 1.4825x over previous
//
#include <hip/hip_runtime.h>
#include <math.h>

#define TPB 256

// ---------------------------------------------------------------------------
// Edge dtype probe: if edge_index is int64 (LE, values < 2^31), every odd
// 32-bit word is zero. flag=1 -> int32 input.
// ---------------------------------------------------------------------------
__global__ __launch_bounds__(TPB) void detect_dtype(const int* __restrict__ e,
                                                    int* __restrict__ flag) {
  __shared__ int found;
  if (threadIdx.x == 0) found = 0;
  __syncthreads();
  int nz = 0;
  for (int i = threadIdx.x; i < 2048; i += TPB)
    nz |= (e[2 * i + 1] != 0) ? 1 : 0;
  if (nz) atomicOr(&found, 1);
  __syncthreads();
  if (threadIdx.x == 0) *flag = found;
}

__global__ __launch_bounds__(TPB) void init_deg(float* __restrict__ deg, int n) {
  int i = blockIdx.x * TPB + threadIdx.x;
  if (i < n) deg[i] = 1.0f;  // self-loop
}

// Convert edges to int32 (int32 or int64 input) and count in-degrees of dst
// (second half of buffer) in the same pass.
__global__ __launch_bounds__(TPB) void convert_count(const void* __restrict__ eptr,
                                                     int* __restrict__ e32,
                                                     float* __restrict__ deg,
                                                     const int* __restrict__ flag,
                                                     int total, int E) {
  int i = blockIdx.x * TPB + threadIdx.x;
  if (i >= total) return;
  int v;
  if (*flag)
    v = ((const int*)eptr)[i];
  else
    v = (int)(((const long long*)eptr)[i]);
  e32[i] = v;
  if (i >= E) unsafeAtomicAdd(&deg[v], 1.0f);
}

// ---------------------------------------------------------------------------
// Device-wide exclusive scan of in-degrees (deg[i]-1), 3 phases.
// ---------------------------------------------------------------------------
// Phase 1: per-block exclusive scan of 256-elem chunk; write block sum.
__global__ __launch_bounds__(TPB) void scan_phase1(const float* __restrict__ deg,
                                                   int* __restrict__ rowptr,
                                                   int* __restrict__ bsum, int n) {
  __shared__ int buf[TPB];
  int tid = threadIdx.x;
  int i = blockIdx.x * TPB + tid;
  int v = (i < n) ? (int)(deg[i] + 0.5f) - 1 : 0;
  buf[tid] = v;
  __syncthreads();
  for (int off = 1; off < TPB; off <<= 1) {
    int t = (tid >= off) ? buf[tid - off] : 0;
    __syncthreads();
    buf[tid] += t;
    __syncthreads();
  }
  if (i < n) rowptr[i] = buf[tid] - v;  // exclusive within block
  if (tid == TPB - 1) bsum[blockIdx.x] = buf[tid];
}

// Phase 2: single block, exclusive scan of nb block sums (chunked w/ carry).
__global__ __launch_bounds__(TPB) void scan_phase2(int* __restrict__ bsum, int nb) {
  __shared__ int buf[TPB];
  __shared__ int carry;
  int tid = threadIdx.x;
  if (tid == 0) carry = 0;
  __syncthreads();
  for (int base = 0; base < nb; base += TPB) {
    int i = base + tid;
    int v = (i < nb) ? bsum[i] : 0;
    buf[tid] = v;
    __syncthreads();
    for (int off = 1; off < TPB; off <<= 1) {
      int t = (tid >= off) ? buf[tid - off] : 0;
      __syncthreads();
      buf[tid] += t;
      __syncthreads();
    }
    if (i < nb) bsum[i] = carry + buf[tid] - v;  // exclusive
    __syncthreads();
    if (tid == TPB - 1) carry += buf[tid];
    __syncthreads();
  }
}

// Phase 3: add block offset; also fold dinv = rsqrt(deg) in-place.
__global__ __launch_bounds__(TPB) void scan_phase3(int* __restrict__ rowptr,
                                                   const int* __restrict__ bsum,
                                                   float* __restrict__ deg, int n) {
  int i = blockIdx.x * TPB + threadIdx.x;
  if (i < n) {
    rowptr[i] += bsum[blockIdx.x];
    deg[i] = rsqrtf(deg[i]);
  }
}

// CSR fill, cursor trick: slot = rowptr[d]++ (atomic). After this kernel,
// rowptr[i] = end offset of node i; start = (i==0) ? 0 : rowptr[i-1].
__global__ __launch_bounds__(TPB) void csr_fill(const int* __restrict__ src,
                                                const int* __restrict__ dst,
                                                int* __restrict__ rowptr,
                                                int* __restrict__ csr_src, int E) {
  int e = blockIdx.x * TPB + threadIdx.x;
  if (e >= E) return;
  int slot = atomicAdd(&rowptr[dst[e]], 1);
  csr_src[slot] = src[e];
}

// ---------------------------------------------------------------------------
// out[r, c] = (A[r,:] @ W[:,c]) * dinv[r]
// ---------------------------------------------------------------------------
template <int K, int NC>
__global__ __launch_bounds__(TPB) void gemm_scale(const float* __restrict__ A,
                                                  const float* __restrict__ W,
                                                  const float* __restrict__ dinv,
                                                  float* __restrict__ out, int nrows) {
  constexpr int ROWS = 8;
  constexpr int GROUPS = TPB / NC;
  constexpr int RPT = ROWS / GROUPS;
  __shared__ float As[ROWS * K];

  int block_row = blockIdx.x * ROWS;
  int tid = threadIdx.x;

  {
    int idx = tid * 4;
    int r = idx / K, c = idx % K;
    int gr = block_row + r;
    float4 v = make_float4(0.f, 0.f, 0.f, 0.f);
    if (gr < nrows) v = *(const float4*)&A[(size_t)gr * K + c];
    *(float4*)&As[idx] = v;
  }
  __syncthreads();

  int c = tid % NC;
  int g = tid / NC;
  int r0 = g * RPT;

  float acc[RPT];
#pragma unroll
  for (int r = 0; r < RPT; r++) acc[r] = 0.f;

  for (int k = 0; k < K; k += 4) {
    float w0 = W[(k + 0) * NC + c];
    float w1 = W[(k + 1) * NC + c];
    float w2 = W[(k + 2) * NC + c];
    float w3 = W[(k + 3) * NC + c];
#pragma unroll
    for (int r = 0; r < RPT; r++) {
      float4 a = *(const float4*)&As[(r0 + r) * K + k];
      acc[r] += a.x * w0 + a.y * w1 + a.z * w2 + a.w * w3;
    }
  }

#pragma unroll
  for (int r = 0; r < RPT; r++) {
    int gr = block_row + r0 + r;
    if (gr < nrows) out[(size_t)gr * NC + c] = acc[r] * dinv[gr];
  }
}

// ---------------------------------------------------------------------------
// Fused CSR aggregation + self-loop + dinv scale + bias + tanh:
//   h[i,:] = tanh((sum_{s in in(i)} t[s,:] + t[i,:]) * dinv[i] + b)
// NC/4 lanes per node, float4 gathers, one coalesced write. No atomics.
// ---------------------------------------------------------------------------
template <int NC>
__global__ __launch_bounds__(TPB) void gcn_aggregate(const int* __restrict__ rowend,
                                                     const int* __restrict__ csr_src,
                                                     const float* __restrict__ t,
                                                     const float* __restrict__ dinv,
                                                     const float* __restrict__ bias,
                                                     float* __restrict__ h, int n) {
  constexpr int LPN = NC / 4;          // lanes per node
  constexpr int NPB = TPB / LPN;       // nodes per block
  int tid = threadIdx.x;
  int node = blockIdx.x * NPB + tid / LPN;
  int lane = tid % LPN;
  if (node >= n) return;

  int start = (node == 0) ? 0 : rowend[node - 1];
  int end = rowend[node];

  float4 acc = make_float4(0.f, 0.f, 0.f, 0.f);
  for (int e = start; e < end; e++) {
    int s = csr_src[e];
    float4 v = *(const float4*)&t[(size_t)s * NC + lane * 4];
    acc.x += v.x; acc.y += v.y; acc.z += v.z; acc.w += v.w;
  }
  float4 self = *(const float4*)&t[(size_t)node * NC + lane * 4];
  float di = dinv[node];
  float4 b = *(const float4*)&bias[lane * 4];
  float4 r;
  r.x = tanhf((acc.x + self.x) * di + b.x);
  r.y = tanhf((acc.y + self.y) * di + b.y);
  r.z = tanhf((acc.z + self.z) * di + b.z);
  r.w = tanhf((acc.w + self.w) * di + b.w);
  *(float4*)&h[(size_t)node * NC + lane * 4] = r;
}

// ---------------------------------------------------------------------------
// out[r] = tanh(h2[r,:] @ Wf1 + bf1) @ Wf2 + bf2 ; one thread per row.
// ---------------------------------------------------------------------------
__global__ __launch_bounds__(TPB) void mlp_head(const float* __restrict__ h2,
                                                const float* __restrict__ Wf1,
                                                const float* __restrict__ bf1,
                                                const float* __restrict__ Wf2,
                                                const float* __restrict__ bf2,
                                                float* __restrict__ out, int n) {
  int row = blockIdx.x * TPB + threadIdx.x;
  if (row >= n) return;
  float acc[32];
#pragma unroll
  for (int j = 0; j < 32; j++) acc[j] = bf1[j];
#pragma unroll 4
  for (int k = 0; k < 64; k += 4) {
    float4 h4 = *(const float4*)&h2[(size_t)row * 64 + k];
    float hv[4] = {h4.x, h4.y, h4.z, h4.w};
#pragma unroll
    for (int kk = 0; kk < 4; kk++)
#pragma unroll
      for (int j = 0; j < 32; j++) acc[j] += hv[kk] * Wf1[(k + kk) * 32 + j];
  }
  float o = bf2[0];
#pragma unroll
  for (int j = 0; j < 32; j++) o += tanhf(acc[j]) * Wf2[j];
  out[row] = o;
}

extern "C" void kernel_launch(void* const* d_in, const int* in_sizes, int n_in,
                              void* d_out, int out_size, void* d_ws, size_t ws_size,
                              hipStream_t stream) {
  const float* x   = (const float*)d_in[0];
  const void*  eix = d_in[1];
  const float* W1  = (const float*)d_in[2];
  const float* b1  = (const float*)d_in[3];
  const float* W2  = (const float*)d_in[4];
  const float* b2  = (const float*)d_in[5];
  const float* Wf1 = (const float*)d_in[6];
  const float* bf1 = (const float*)d_in[7];
  const float* Wf2 = (const float*)d_in[8];
  const float* bf2 = (const float*)d_in[9];
  float* out = (float*)d_out;

  const int N = in_sizes[0] / 128;
  const int E = in_sizes[1] / 2;
  const int nb = (N + TPB - 1) / TPB;

  // workspace layout (16B aligned)
  char* ws = (char*)d_ws;
  size_t off = 0;
  float* deg = (float*)(ws + off); off += (size_t)N * 4;        // counts -> dinv
  int* flag = (int*)(ws + off); off += 64;
  int* e32 = (int*)(ws + off); off += (size_t)2 * E * 4;        // src | dst int32
  int* rowptr = (int*)(ws + off); off += ((size_t)N + 4) * 4;   // excl psum -> rowend
  int* bsum = (int*)(ws + off); off += ((size_t)nb + 4) * 4;    // block sums
  int* csr_src = (int*)(ws + off); off += (size_t)E * 4;
  off = (off + 15) & ~(size_t)15;
  float* t1 = (float*)(ws + off); off += (size_t)N * 128 * 4;   // t1; later t2|h2
  float* h1 = (float*)(ws + off); off += (size_t)N * 128 * 4;
  int* src = e32;
  int* dst = e32 + E;
  float* t2 = t1;                        // N*64, reuses t1 region
  float* h2 = t1 + (size_t)N * 64;       // N*64
  (void)ws_size; (void)n_in; (void)out_size;

  // graph preprocessing: dtype, degrees, scan -> rowptr, dinv, CSR
  detect_dtype<<<1, TPB, 0, stream>>>((const int*)eix, flag);
  init_deg<<<nb, TPB, 0, stream>>>(deg, N);
  convert_count<<<(2 * E + TPB - 1) / TPB, TPB, 0, stream>>>(eix, e32, deg, flag, 2 * E, E);
  scan_phase1<<<nb, TPB, 0, stream>>>(deg, rowptr, bsum, N);
  scan_phase2<<<1, TPB, 0, stream>>>(bsum, nb);
  scan_phase3<<<nb, TPB, 0, stream>>>(rowptr, bsum, deg, N);
  csr_fill<<<(E + TPB - 1) / TPB, TPB, 0, stream>>>(src, dst, rowptr, csr_src, E);

  // layer 1: t1 = (x@W1)*dinv ; h1 = tanh((gather(t1)+t1)*dinv+b1)
  gemm_scale<128, 128><<<(N + 7) / 8, TPB, 0, stream>>>(x, W1, deg, t1, N);
  gcn_aggregate<128><<<(N + 7) / 8, TPB, 0, stream>>>(rowptr, csr_src, t1, deg, b1, h1, N);

  // layer 2: t2 = (h1@W2)*dinv ; h2 = tanh((gather(t2)+t2)*dinv+b2)
  gemm_scale<128, 64><<<(N + 7) / 8, TPB, 0, stream>>>(h1, W2, deg, t2, N);
  gcn_aggregate<64><<<(N + 15) / 16, TPB, 0, stream>>>(rowptr, csr_src, t2, deg, b2, h2, N);

  // MLP head
  mlp_head<<<nb, TPB, 0, stream>>>(h2, Wf1, bf1, Wf2, bf2, out, N);
}

// Round 4
// 372.281 us; speedup vs baseline: 6.1499x; 1.2156x over previous
//
#include <hip/hip_runtime.h>
#include <math.h>

#define TPB 256

// ---------------------------------------------------------------------------
// Edge dtype probe: if edge_index is int64 (LE, values < 2^31), every odd
// 32-bit word is zero. flag=1 -> int32 input.
// ---------------------------------------------------------------------------
__global__ __launch_bounds__(TPB) void detect_dtype(const int* __restrict__ e,
                                                    int* __restrict__ flag) {
  __shared__ int found;
  if (threadIdx.x == 0) found = 0;
  __syncthreads();
  int nz = 0;
  for (int i = threadIdx.x; i < 2048; i += TPB)
    nz |= (e[2 * i + 1] != 0) ? 1 : 0;
  if (nz) atomicOr(&found, 1);
  __syncthreads();
  if (threadIdx.x == 0) *flag = found;
}

__global__ __launch_bounds__(TPB) void init_deg(float* __restrict__ deg, int n) {
  int i = blockIdx.x * TPB + threadIdx.x;
  if (i < n) deg[i] = 1.0f;  // self-loop
}

// Convert edges to int32 (int32 or int64 input) and count in-degrees of dst
// (second half of buffer) in the same pass.
__global__ __launch_bounds__(TPB) void convert_count(const void* __restrict__ eptr,
                                                     int* __restrict__ e32,
                                                     float* __restrict__ deg,
                                                     const int* __restrict__ flag,
                                                     int total, int E) {
  int i = blockIdx.x * TPB + threadIdx.x;
  if (i >= total) return;
  int v;
  if (*flag)
    v = ((const int*)eptr)[i];
  else
    v = (int)(((const long long*)eptr)[i]);
  e32[i] = v;
  if (i >= E) unsafeAtomicAdd(&deg[v], 1.0f);
}

// ---------------------------------------------------------------------------
// Device-wide exclusive scan of in-degrees (deg[i]-1), 3 phases.
// ---------------------------------------------------------------------------
__global__ __launch_bounds__(TPB) void scan_phase1(const float* __restrict__ deg,
                                                   int* __restrict__ rowptr,
                                                   int* __restrict__ bsum, int n) {
  __shared__ int buf[TPB];
  int tid = threadIdx.x;
  int i = blockIdx.x * TPB + tid;
  int v = (i < n) ? (int)(deg[i] + 0.5f) - 1 : 0;
  buf[tid] = v;
  __syncthreads();
  for (int off = 1; off < TPB; off <<= 1) {
    int t = (tid >= off) ? buf[tid - off] : 0;
    __syncthreads();
    buf[tid] += t;
    __syncthreads();
  }
  if (i < n) rowptr[i] = buf[tid] - v;  // exclusive within block
  if (tid == TPB - 1) bsum[blockIdx.x] = buf[tid];
}

__global__ __launch_bounds__(TPB) void scan_phase2(int* __restrict__ bsum, int nb) {
  __shared__ int buf[TPB];
  __shared__ int carry;
  int tid = threadIdx.x;
  if (tid == 0) carry = 0;
  __syncthreads();
  for (int base = 0; base < nb; base += TPB) {
    int i = base + tid;
    int v = (i < nb) ? bsum[i] : 0;
    buf[tid] = v;
    __syncthreads();
    for (int off = 1; off < TPB; off <<= 1) {
      int t = (tid >= off) ? buf[tid - off] : 0;
      __syncthreads();
      buf[tid] += t;
      __syncthreads();
    }
    if (i < nb) bsum[i] = carry + buf[tid] - v;  // exclusive
    __syncthreads();
    if (tid == TPB - 1) carry += buf[tid];
    __syncthreads();
  }
}

__global__ __launch_bounds__(TPB) void scan_phase3(int* __restrict__ rowptr,
                                                   const int* __restrict__ bsum,
                                                   float* __restrict__ deg, int n) {
  int i = blockIdx.x * TPB + threadIdx.x;
  if (i < n) {
    rowptr[i] += bsum[blockIdx.x];
    deg[i] = rsqrtf(deg[i]);
  }
}

// CSR fill, cursor trick: slot = rowptr[d]++ (atomic). After this kernel,
// rowptr[i] = end offset of node i; start = (i==0) ? 0 : rowptr[i-1].
__global__ __launch_bounds__(TPB) void csr_fill(const int* __restrict__ src,
                                                const int* __restrict__ dst,
                                                int* __restrict__ rowptr,
                                                int* __restrict__ csr_src, int E) {
  int e = blockIdx.x * TPB + threadIdx.x;
  if (e >= E) return;
  int slot = atomicAdd(&rowptr[dst[e]], 1);
  csr_src[slot] = src[e];
}

// ---------------------------------------------------------------------------
// out[r, c] = (A[r,:] @ W[:,c]) * dinv[r]     fp32, K=128 fixed.
// Block: 256 threads -> 64 rows x NC cols, BK=32 K-tiles.
// A staged transposed in LDS (stride 68, b128-aligned); W staged direct.
// Per-thread register tile: 4 rows x (NC/16) cols.
// __launch_bounds__(256,4): 4 blocks/CU target -> VGPR<=128, 16 waves/CU.
// ---------------------------------------------------------------------------
template <int NC>
__global__ __launch_bounds__(TPB, 4) void gemm_fast(const float* __restrict__ A,
                                                    const float* __restrict__ W,
                                                    const float* __restrict__ dinv,
                                                    float* __restrict__ out, int nrows) {
  constexpr int K = 128, TM = 64, BK = 32;
  constexpr int CPT = NC / 16;        // cols per thread: 8 (NC=128) or 4 (NC=64)
  constexpr int AST = TM + 4;         // 68: keeps b128 4-float alignment
  __shared__ float As[BK * AST];      // [k][r] transposed
  __shared__ float Ws[BK * NC];       // [k][c]

  const int tid = threadIdx.x;
  const int tx = tid % 16;            // col group: cols tx*4 (+64 if NC=128)
  const int ty = tid / 16;            // row group: rows ty*4
  const int r0 = ty * 4;
  const int block_row = blockIdx.x * TM;

  float acc[4][CPT];
#pragma unroll
  for (int r = 0; r < 4; r++)
#pragma unroll
    for (int c = 0; c < CPT; c++) acc[r][c] = 0.f;

  for (int k0 = 0; k0 < K; k0 += BK) {
    // stage A 64x32 transposed: 2 float4 loads/thread
#pragma unroll
    for (int i = 0; i < 2; i++) {
      int lid = tid + i * TPB;        // 512 float4 slots
      int r = lid / 8;                // 8 float4 per row
      int kk = (lid % 8) * 4;
      int gr = block_row + r;
      float4 v = make_float4(0.f, 0.f, 0.f, 0.f);
      if (gr < nrows) v = *(const float4*)&A[(size_t)gr * K + k0 + kk];
      As[(kk + 0) * AST + r] = v.x;
      As[(kk + 1) * AST + r] = v.y;
      As[(kk + 2) * AST + r] = v.z;
      As[(kk + 3) * AST + r] = v.w;
    }
    // stage W BKxNC: (BK*NC/4)/256 float4 per thread
#pragma unroll
    for (int i = 0; i < (BK * NC) / (4 * TPB); i++) {
      int lid = tid + i * TPB;
      int k = lid / (NC / 4);
      int c = (lid % (NC / 4)) * 4;
      *(float4*)&Ws[k * NC + c] = *(const float4*)&W[(size_t)(k0 + k) * NC + c];
    }
    __syncthreads();

#pragma unroll
    for (int k = 0; k < BK; k++) {
      float4 a = *(const float4*)&As[k * AST + r0];
      float av[4] = {a.x, a.y, a.z, a.w};
      float4 w0 = *(const float4*)&Ws[k * NC + tx * 4];
      float wv[CPT];
      wv[0] = w0.x; wv[1] = w0.y; wv[2] = w0.z; wv[3] = w0.w;
      if (NC == 128) {
        float4 w1 = *(const float4*)&Ws[k * NC + 64 + tx * 4];
        wv[4] = w1.x; wv[5] = w1.y; wv[6] = w1.z; wv[7] = w1.w;
      }
#pragma unroll
      for (int r = 0; r < 4; r++)
#pragma unroll
        for (int c = 0; c < CPT; c++) acc[r][c] += av[r] * wv[c];
    }
    __syncthreads();
  }

#pragma unroll
  for (int r = 0; r < 4; r++) {
    int gr = block_row + r0 + r;
    if (gr >= nrows) continue;
    float di = dinv[gr];
    float4 o0 = make_float4(acc[r][0] * di, acc[r][1] * di, acc[r][2] * di,
                            acc[r][3] * di);
    *(float4*)&out[(size_t)gr * NC + tx * 4] = o0;
    if (NC == 128) {
      float4 o1 = make_float4(acc[r][4] * di, acc[r][5] * di, acc[r][6] * di,
                              acc[r][7] * di);
      *(float4*)&out[(size_t)gr * NC + 64 + tx * 4] = o1;
    }
  }
}

// ---------------------------------------------------------------------------
// Fused CSR aggregation + self-loop + dinv scale + bias + tanh:
//   h[i,:] = tanh((sum_{s in in(i)} t[s,:] + t[i,:]) * dinv[i] + b)
// ---------------------------------------------------------------------------
template <int NC>
__global__ __launch_bounds__(TPB) void gcn_aggregate(const int* __restrict__ rowend,
                                                     const int* __restrict__ csr_src,
                                                     const float* __restrict__ t,
                                                     const float* __restrict__ dinv,
                                                     const float* __restrict__ bias,
                                                     float* __restrict__ h, int n) {
  constexpr int LPN = NC / 4;          // lanes per node
  constexpr int NPB = TPB / LPN;       // nodes per block
  int tid = threadIdx.x;
  int node = blockIdx.x * NPB + tid / LPN;
  int lane = tid % LPN;
  if (node >= n) return;

  int start = (node == 0) ? 0 : rowend[node - 1];
  int end = rowend[node];

  float4 acc = make_float4(0.f, 0.f, 0.f, 0.f);
  for (int e = start; e < end; e++) {
    int s = csr_src[e];
    float4 v = *(const float4*)&t[(size_t)s * NC + lane * 4];
    acc.x += v.x; acc.y += v.y; acc.z += v.z; acc.w += v.w;
  }
  float4 self = *(const float4*)&t[(size_t)node * NC + lane * 4];
  float di = dinv[node];
  float4 b = *(const float4*)&bias[lane * 4];
  float4 r;
  r.x = tanhf((acc.x + self.x) * di + b.x);
  r.y = tanhf((acc.y + self.y) * di + b.y);
  r.z = tanhf((acc.z + self.z) * di + b.z);
  r.w = tanhf((acc.w + self.w) * di + b.w);
  *(float4*)&h[(size_t)node * NC + lane * 4] = r;
}

// ---------------------------------------------------------------------------
// out[r] = tanh(h2[r,:] @ Wf1 + bf1) @ Wf2 + bf2 ; one thread per row.
// ---------------------------------------------------------------------------
__global__ __launch_bounds__(TPB) void mlp_head(const float* __restrict__ h2,
                                                const float* __restrict__ Wf1,
                                                const float* __restrict__ bf1,
                                                const float* __restrict__ Wf2,
                                                const float* __restrict__ bf2,
                                                float* __restrict__ out, int n) {
  int row = blockIdx.x * TPB + threadIdx.x;
  if (row >= n) return;
  float acc[32];
#pragma unroll
  for (int j = 0; j < 32; j++) acc[j] = bf1[j];
#pragma unroll 4
  for (int k = 0; k < 64; k += 4) {
    float4 h4 = *(const float4*)&h2[(size_t)row * 64 + k];
    float hv[4] = {h4.x, h4.y, h4.z, h4.w};
#pragma unroll
    for (int kk = 0; kk < 4; kk++)
#pragma unroll
      for (int j = 0; j < 32; j++) acc[j] += hv[kk] * Wf1[(k + kk) * 32 + j];
  }
  float o = bf2[0];
#pragma unroll
  for (int j = 0; j < 32; j++) o += tanhf(acc[j]) * Wf2[j];
  out[row] = o;
}

extern "C" void kernel_launch(void* const* d_in, const int* in_sizes, int n_in,
                              void* d_out, int out_size, void* d_ws, size_t ws_size,
                              hipStream_t stream) {
  const float* x   = (const float*)d_in[0];
  const void*  eix = d_in[1];
  const float* W1  = (const float*)d_in[2];
  const float* b1  = (const float*)d_in[3];
  const float* W2  = (const float*)d_in[4];
  const float* b2  = (const float*)d_in[5];
  const float* Wf1 = (const float*)d_in[6];
  const float* bf1 = (const float*)d_in[7];
  const float* Wf2 = (const float*)d_in[8];
  const float* bf2 = (const float*)d_in[9];
  float* out = (float*)d_out;

  const int N = in_sizes[0] / 128;
  const int E = in_sizes[1] / 2;
  const int nb = (N + TPB - 1) / TPB;

  // workspace layout (16B aligned)
  char* ws = (char*)d_ws;
  size_t off = 0;
  float* deg = (float*)(ws + off); off += (size_t)N * 4;        // counts -> dinv
  int* flag = (int*)(ws + off); off += 64;
  int* e32 = (int*)(ws + off); off += (size_t)2 * E * 4;        // src | dst int32
  int* rowptr = (int*)(ws + off); off += ((size_t)N + 4) * 4;   // excl psum -> rowend
  int* bsum = (int*)(ws + off); off += ((size_t)nb + 4) * 4;    // block sums
  int* csr_src = (int*)(ws + off); off += (size_t)E * 4;
  off = (off + 15) & ~(size_t)15;
  float* t1 = (float*)(ws + off); off += (size_t)N * 128 * 4;   // t1; later t2|h2
  float* h1 = (float*)(ws + off); off += (size_t)N * 128 * 4;
  int* src = e32;
  int* dst = e32 + E;
  float* t2 = t1;                        // N*64, reuses t1 region
  float* h2 = t1 + (size_t)N * 64;       // N*64
  (void)ws_size; (void)n_in; (void)out_size;

  // graph preprocessing: dtype, degrees, scan -> rowptr, dinv, CSR
  detect_dtype<<<1, TPB, 0, stream>>>((const int*)eix, flag);
  init_deg<<<nb, TPB, 0, stream>>>(deg, N);
  convert_count<<<(2 * E + TPB - 1) / TPB, TPB, 0, stream>>>(eix, e32, deg, flag, 2 * E, E);
  scan_phase1<<<nb, TPB, 0, stream>>>(deg, rowptr, bsum, N);
  scan_phase2<<<1, TPB, 0, stream>>>(bsum, nb);
  scan_phase3<<<nb, TPB, 0, stream>>>(rowptr, bsum, deg, N);
  csr_fill<<<(E + TPB - 1) / TPB, TPB, 0, stream>>>(src, dst, rowptr, csr_src, E);

  // layer 1: t1 = (x@W1)*dinv ; h1 = tanh((gather(t1)+t1)*dinv+b1)
  gemm_fast<128><<<(N + 63) / 64, TPB, 0, stream>>>(x, W1, deg, t1, N);
  gcn_aggregate<128><<<(N + 7) / 8, TPB, 0, stream>>>(rowptr, csr_src, t1, deg, b1, h1, N);

  // layer 2: t2 = (h1@W2)*dinv ; h2 = tanh((gather(t2)+t2)*dinv+b2)
  gemm_fast<64><<<(N + 63) / 64, TPB, 0, stream>>>(h1, W2, deg, t2, N);
  gcn_aggregate<64><<<(N + 15) / 16, TPB, 0, stream>>>(rowptr, csr_src, t2, deg, b2, h2, N);

  // MLP head
  mlp_head<<<nb, TPB, 0, stream>>>(h2, Wf1, bf1, Wf2, bf2, out, N);
}

// Round 5
// 332.454 us; speedup vs baseline: 6.8866x; 1.1198x over previous
//
#include <hip/hip_runtime.h>
#include <hip/hip_fp16.h>
#include <math.h>

#define TPB 256

// ---------------------------------------------------------------------------
// Edge dtype probe: if edge_index is int64 (LE, values < 2^31), every odd
// 32-bit word is zero. flag=1 -> int32 input.
// ---------------------------------------------------------------------------
__global__ __launch_bounds__(TPB) void detect_dtype(const int* __restrict__ e,
                                                    int* __restrict__ flag) {
  __shared__ int found;
  if (threadIdx.x == 0) found = 0;
  __syncthreads();
  int nz = 0;
  for (int i = threadIdx.x; i < 2048; i += TPB)
    nz |= (e[2 * i + 1] != 0) ? 1 : 0;
  if (nz) atomicOr(&found, 1);
  __syncthreads();
  if (threadIdx.x == 0) *flag = found;
}

__global__ __launch_bounds__(TPB) void init_deg(float* __restrict__ deg, int n) {
  int i = blockIdx.x * TPB + threadIdx.x;
  if (i < n) deg[i] = 1.0f;  // self-loop
}

// Convert edges to int32 (int32 or int64 input) and count in-degrees of dst
// (second half of buffer) in the same pass.
__global__ __launch_bounds__(TPB) void convert_count(const void* __restrict__ eptr,
                                                     int* __restrict__ e32,
                                                     float* __restrict__ deg,
                                                     const int* __restrict__ flag,
                                                     int total, int E) {
  int i = blockIdx.x * TPB + threadIdx.x;
  if (i >= total) return;
  int v;
  if (*flag)
    v = ((const int*)eptr)[i];
  else
    v = (int)(((const long long*)eptr)[i]);
  e32[i] = v;
  if (i >= E) unsafeAtomicAdd(&deg[v], 1.0f);
}

// ---------------------------------------------------------------------------
// Device-wide exclusive scan of in-degrees (deg[i]-1), 3 phases.
// ---------------------------------------------------------------------------
__global__ __launch_bounds__(TPB) void scan_phase1(const float* __restrict__ deg,
                                                   int* __restrict__ rowptr,
                                                   int* __restrict__ bsum, int n) {
  __shared__ int buf[TPB];
  int tid = threadIdx.x;
  int i = blockIdx.x * TPB + tid;
  int v = (i < n) ? (int)(deg[i] + 0.5f) - 1 : 0;
  buf[tid] = v;
  __syncthreads();
  for (int off = 1; off < TPB; off <<= 1) {
    int t = (tid >= off) ? buf[tid - off] : 0;
    __syncthreads();
    buf[tid] += t;
    __syncthreads();
  }
  if (i < n) rowptr[i] = buf[tid] - v;  // exclusive within block
  if (tid == TPB - 1) bsum[blockIdx.x] = buf[tid];
}

__global__ __launch_bounds__(TPB) void scan_phase2(int* __restrict__ bsum, int nb) {
  __shared__ int buf[TPB];
  __shared__ int carry;
  int tid = threadIdx.x;
  if (tid == 0) carry = 0;
  __syncthreads();
  for (int base = 0; base < nb; base += TPB) {
    int i = base + tid;
    int v = (i < nb) ? bsum[i] : 0;
    buf[tid] = v;
    __syncthreads();
    for (int off = 1; off < TPB; off <<= 1) {
      int t = (tid >= off) ? buf[tid - off] : 0;
      __syncthreads();
      buf[tid] += t;
      __syncthreads();
    }
    if (i < nb) bsum[i] = carry + buf[tid] - v;  // exclusive
    __syncthreads();
    if (tid == TPB - 1) carry += buf[tid];
    __syncthreads();
  }
}

__global__ __launch_bounds__(TPB) void scan_phase3(int* __restrict__ rowptr,
                                                   const int* __restrict__ bsum,
                                                   float* __restrict__ deg, int n) {
  int i = blockIdx.x * TPB + threadIdx.x;
  if (i < n) {
    rowptr[i] += bsum[blockIdx.x];
    deg[i] = rsqrtf(deg[i]);
  }
}

// CSR fill, cursor trick: slot = rowptr[d]++ (atomic). After this kernel,
// rowptr[i] = end offset of node i; start = (i==0) ? 0 : rowptr[i-1].
__global__ __launch_bounds__(TPB) void csr_fill(const int* __restrict__ src,
                                                const int* __restrict__ dst,
                                                int* __restrict__ rowptr,
                                                int* __restrict__ csr_src, int E) {
  int e = blockIdx.x * TPB + threadIdx.x;
  if (e >= E) return;
  int slot = atomicAdd(&rowptr[dst[e]], 1);
  csr_src[slot] = src[e];
}

// ---------------------------------------------------------------------------
// t[r, c] = half((A[r,:] @ W[:,c]) * dinv[r])     fp32 math, K=128 fixed.
// Block: 256 threads -> 64 rows x NC cols, BK=32 K-tiles. fp16 output.
// ---------------------------------------------------------------------------
template <int NC>
__global__ __launch_bounds__(TPB, 4) void gemm_fast(const float* __restrict__ A,
                                                    const float* __restrict__ W,
                                                    const float* __restrict__ dinv,
                                                    __half* __restrict__ out, int nrows) {
  constexpr int K = 128, TM = 64, BK = 32;
  constexpr int CPT = NC / 16;        // cols per thread: 8 (NC=128) or 4 (NC=64)
  constexpr int AST = TM + 4;         // 68: keeps b128 4-float alignment
  __shared__ float As[BK * AST];      // [k][r] transposed
  __shared__ float Ws[BK * NC];       // [k][c]

  const int tid = threadIdx.x;
  const int tx = tid % 16;            // col group: cols tx*4 (+64 if NC=128)
  const int ty = tid / 16;            // row group: rows ty*4
  const int r0 = ty * 4;
  const int block_row = blockIdx.x * TM;

  float acc[4][CPT];
#pragma unroll
  for (int r = 0; r < 4; r++)
#pragma unroll
    for (int c = 0; c < CPT; c++) acc[r][c] = 0.f;

  for (int k0 = 0; k0 < K; k0 += BK) {
#pragma unroll
    for (int i = 0; i < 2; i++) {
      int lid = tid + i * TPB;        // 512 float4 slots
      int r = lid / 8;                // 8 float4 per row
      int kk = (lid % 8) * 4;
      int gr = block_row + r;
      float4 v = make_float4(0.f, 0.f, 0.f, 0.f);
      if (gr < nrows) v = *(const float4*)&A[(size_t)gr * K + k0 + kk];
      As[(kk + 0) * AST + r] = v.x;
      As[(kk + 1) * AST + r] = v.y;
      As[(kk + 2) * AST + r] = v.z;
      As[(kk + 3) * AST + r] = v.w;
    }
#pragma unroll
    for (int i = 0; i < (BK * NC) / (4 * TPB); i++) {
      int lid = tid + i * TPB;
      int k = lid / (NC / 4);
      int c = (lid % (NC / 4)) * 4;
      *(float4*)&Ws[k * NC + c] = *(const float4*)&W[(size_t)(k0 + k) * NC + c];
    }
    __syncthreads();

#pragma unroll
    for (int k = 0; k < BK; k++) {
      float4 a = *(const float4*)&As[k * AST + r0];
      float av[4] = {a.x, a.y, a.z, a.w};
      float4 w0 = *(const float4*)&Ws[k * NC + tx * 4];
      float wv[CPT];
      wv[0] = w0.x; wv[1] = w0.y; wv[2] = w0.z; wv[3] = w0.w;
      if (NC == 128) {
        float4 w1 = *(const float4*)&Ws[k * NC + 64 + tx * 4];
        wv[4] = w1.x; wv[5] = w1.y; wv[6] = w1.z; wv[7] = w1.w;
      }
#pragma unroll
      for (int r = 0; r < 4; r++)
#pragma unroll
        for (int c = 0; c < CPT; c++) acc[r][c] += av[r] * wv[c];
    }
    __syncthreads();
  }

  union H4 { __half2 h[2]; uint2 u; };
#pragma unroll
  for (int r = 0; r < 4; r++) {
    int gr = block_row + r0 + r;
    if (gr >= nrows) continue;
    float di = dinv[gr];
    H4 p;
    p.h[0] = __float22half2_rn(make_float2(acc[r][0] * di, acc[r][1] * di));
    p.h[1] = __float22half2_rn(make_float2(acc[r][2] * di, acc[r][3] * di));
    *(uint2*)&out[(size_t)gr * NC + tx * 4] = p.u;
    if (NC == 128) {
      H4 q;
      q.h[0] = __float22half2_rn(make_float2(acc[r][4] * di, acc[r][5] * di));
      q.h[1] = __float22half2_rn(make_float2(acc[r][6] * di, acc[r][7] * di));
      *(uint2*)&out[(size_t)gr * NC + 64 + tx * 4] = q.u;
    }
  }
}

// ---------------------------------------------------------------------------
// Fused CSR aggregation (fp16 payload, fp32 accumulate) + self-loop + dinv
// scale + bias + tanh:
//   h[i,:] = tanh((sum_{s in in(i)} t[s,:] + t[i,:]) * dinv[i] + b)
// 16 lanes/node (4 nodes per wave); CPL = NC/16 halves per lane.
// ---------------------------------------------------------------------------
template <int NC>
__global__ __launch_bounds__(TPB) void gcn_aggregate(const int* __restrict__ rowend,
                                                     const int* __restrict__ csr_src,
                                                     const __half* __restrict__ t,
                                                     const float* __restrict__ dinv,
                                                     const float* __restrict__ bias,
                                                     float* __restrict__ h, int n) {
  constexpr int LPN = 16;              // lanes per node
  constexpr int CPL = NC / LPN;        // 8 (NC=128) or 4 (NC=64) halves/lane
  constexpr int NPB = TPB / LPN;       // 16 nodes per block
  int tid = threadIdx.x;
  int node = blockIdx.x * NPB + tid / LPN;
  int lane = tid % LPN;
  if (node >= n) return;

  int start = (node == 0) ? 0 : rowend[node - 1];
  int end = rowend[node];
  const __half* tp = t + (size_t)lane * CPL;

  float acc[CPL];
#pragma unroll
  for (int c = 0; c < CPL; c++) acc[c] = 0.f;

  union Ld { uint4 u4; uint2 u2; __half2 h[4]; };
  for (int e = start; e < end; e++) {
    int s = csr_src[e];
    Ld v;
    if (CPL == 8) v.u4 = *(const uint4*)&tp[(size_t)s * NC];
    else          v.u2 = *(const uint2*)&tp[(size_t)s * NC];
#pragma unroll
    for (int c = 0; c < CPL / 2; c++) {
      float2 f = __half22float2(v.h[c]);
      acc[2 * c] += f.x;
      acc[2 * c + 1] += f.y;
    }
  }
  // self-loop term
  {
    Ld v;
    if (CPL == 8) v.u4 = *(const uint4*)&tp[(size_t)node * NC];
    else          v.u2 = *(const uint2*)&tp[(size_t)node * NC];
#pragma unroll
    for (int c = 0; c < CPL / 2; c++) {
      float2 f = __half22float2(v.h[c]);
      acc[2 * c] += f.x;
      acc[2 * c + 1] += f.y;
    }
  }

  float di = dinv[node];
  float* hp = &h[(size_t)node * NC + lane * CPL];
  const float* bp = &bias[lane * CPL];
#pragma unroll
  for (int c = 0; c < CPL; c += 4) {
    float4 b = *(const float4*)&bp[c];
    float4 r;
    r.x = tanhf(acc[c + 0] * di + b.x);
    r.y = tanhf(acc[c + 1] * di + b.y);
    r.z = tanhf(acc[c + 2] * di + b.z);
    r.w = tanhf(acc[c + 3] * di + b.w);
    *(float4*)&hp[c] = r;
  }
}

// ---------------------------------------------------------------------------
// out[r] = tanh(h2[r,:] @ Wf1 + bf1) @ Wf2 + bf2 ; one thread per row.
// ---------------------------------------------------------------------------
__global__ __launch_bounds__(TPB) void mlp_head(const float* __restrict__ h2,
                                                const float* __restrict__ Wf1,
                                                const float* __restrict__ bf1,
                                                const float* __restrict__ Wf2,
                                                const float* __restrict__ bf2,
                                                float* __restrict__ out, int n) {
  int row = blockIdx.x * TPB + threadIdx.x;
  if (row >= n) return;
  float acc[32];
#pragma unroll
  for (int j = 0; j < 32; j++) acc[j] = bf1[j];
#pragma unroll 4
  for (int k = 0; k < 64; k += 4) {
    float4 h4 = *(const float4*)&h2[(size_t)row * 64 + k];
    float hv[4] = {h4.x, h4.y, h4.z, h4.w};
#pragma unroll
    for (int kk = 0; kk < 4; kk++)
#pragma unroll
      for (int j = 0; j < 32; j++) acc[j] += hv[kk] * Wf1[(k + kk) * 32 + j];
  }
  float o = bf2[0];
#pragma unroll
  for (int j = 0; j < 32; j++) o += tanhf(acc[j]) * Wf2[j];
  out[row] = o;
}

extern "C" void kernel_launch(void* const* d_in, const int* in_sizes, int n_in,
                              void* d_out, int out_size, void* d_ws, size_t ws_size,
                              hipStream_t stream) {
  const float* x   = (const float*)d_in[0];
  const void*  eix = d_in[1];
  const float* W1  = (const float*)d_in[2];
  const float* b1  = (const float*)d_in[3];
  const float* W2  = (const float*)d_in[4];
  const float* b2  = (const float*)d_in[5];
  const float* Wf1 = (const float*)d_in[6];
  const float* bf1 = (const float*)d_in[7];
  const float* Wf2 = (const float*)d_in[8];
  const float* bf2 = (const float*)d_in[9];
  float* out = (float*)d_out;

  const int N = in_sizes[0] / 128;
  const int E = in_sizes[1] / 2;
  const int nb = (N + TPB - 1) / TPB;

  // workspace layout (16B aligned)
  char* ws = (char*)d_ws;
  size_t off = 0;
  float* deg = (float*)(ws + off); off += (size_t)N * 4;        // counts -> dinv
  int* flag = (int*)(ws + off); off += 64;
  int* e32 = (int*)(ws + off); off += (size_t)2 * E * 4;        // src | dst int32
  int* rowptr = (int*)(ws + off); off += ((size_t)N + 4) * 4;   // excl psum -> rowend
  int* bsum = (int*)(ws + off); off += ((size_t)nb + 4) * 4;    // block sums
  int* csr_src = (int*)(ws + off); off += (size_t)E * 4;
  off = (off + 15) & ~(size_t)15;
  __half* t1 = (__half*)(ws + off); off += (size_t)N * 128 * 2; // fp16 t1 / t2
  float* h1 = (float*)(ws + off); off += (size_t)N * 128 * 4;
  float* h2 = (float*)(ws + off); off += (size_t)N * 64 * 4;
  int* src = e32;
  int* dst = e32 + E;
  __half* t2 = t1;                     // N*64 halves, reuses t1 region
  (void)ws_size; (void)n_in; (void)out_size;

  // graph preprocessing: dtype, degrees, scan -> rowptr, dinv, CSR
  detect_dtype<<<1, TPB, 0, stream>>>((const int*)eix, flag);
  init_deg<<<nb, TPB, 0, stream>>>(deg, N);
  convert_count<<<(2 * E + TPB - 1) / TPB, TPB, 0, stream>>>(eix, e32, deg, flag, 2 * E, E);
  scan_phase1<<<nb, TPB, 0, stream>>>(deg, rowptr, bsum, N);
  scan_phase2<<<1, TPB, 0, stream>>>(bsum, nb);
  scan_phase3<<<nb, TPB, 0, stream>>>(rowptr, bsum, deg, N);
  csr_fill<<<(E + TPB - 1) / TPB, TPB, 0, stream>>>(src, dst, rowptr, csr_src, E);

  // layer 1: t1 = half((x@W1)*dinv) ; h1 = tanh((gather(t1)+t1)*dinv+b1)
  gemm_fast<128><<<(N + 63) / 64, TPB, 0, stream>>>(x, W1, deg, t1, N);
  gcn_aggregate<128><<<(N + 15) / 16, TPB, 0, stream>>>(rowptr, csr_src, t1, deg, b1, h1, N);

  // layer 2: t2 = half((h1@W2)*dinv) ; h2 = tanh((gather(t2)+t2)*dinv+b2)
  gemm_fast<64><<<(N + 63) / 64, TPB, 0, stream>>>(h1, W2, deg, t2, N);
  gcn_aggregate<64><<<(N + 15) / 16, TPB, 0, stream>>>(rowptr, csr_src, t2, deg, b2, h2, N);

  // MLP head
  mlp_head<<<nb, TPB, 0, stream>>>(h2, Wf1, bf1, Wf2, bf2, out, N);
}